// Round 9
// baseline (529.599 us; speedup 1.0000x reference)
//
#include <hip/hip_runtime.h>
#include <hip/hip_bf16.h>
#include <cstdint>

#define TB 256
#define TBG 512

typedef short short8 __attribute__((ext_vector_type(8)));
typedef float f32x4 __attribute__((ext_vector_type(4)));

constexpr int B_N = 4096, I_N = 128, J_N = 512, G_N = 300;
constexpr int K1 = I_N * G_N;            // 38400 per d
constexpr int BM = 128, BN = 512;        // full-J block; 8 waves = 1x8 over J (wave tile 128x64)
constexpr int NSP = 8;                   // 8 i-chunks of 16
constexpr int IC = 16;
constexpr float INV2PI = 0.15915494309189535f;

// fcb2 layout: [sp][g][kg][j][8e] bf16, kg = d*2 + ih, i = sp*16 + ih*8 + e
constexpr int GSTRIDE = 4 * 512 * 8;                // ushorts per g = 16384
constexpr size_t SPSTRIDE = (size_t)G_N * GSTRIDE;  // per sp

__device__ __forceinline__ ushort f2bf(float f) {
    unsigned int u = __float_as_uint(f);
    return (ushort)((u + 0x7FFFu + ((u >> 16) & 1u)) >> 16);
}

__device__ __forceinline__ float fract_(float x) {
#if __has_builtin(__builtin_amdgcn_fractf)
    return __builtin_amdgcn_fractf(x);
#else
    return x - floorf(x);
#endif
}

// HW packed f32x2 -> bf16x2 (RNE) — v_cvt_pk_bf16_f32 on gfx950
__device__ __forceinline__ unsigned int pack_bf2(float a, float b) {
    __hip_bfloat162 h = __float22bfloat162_rn(make_float2(a, b));
    unsigned int u;
    __builtin_memcpy(&u, &h, 4);
    return u;
}

typedef __attribute__((address_space(3))) unsigned int lds_u32_t;
typedef __attribute__((address_space(1))) const unsigned int glb_u32_t;

__device__ __forceinline__ void llds16(const void* g, void* l) {
    __builtin_amdgcn_global_load_lds(
        reinterpret_cast<glb_u32_t*>(reinterpret_cast<uintptr_t>(g)),
        reinterpret_cast<lds_u32_t*>((unsigned int)reinterpret_cast<uintptr_t>(l)),
        16, 0, 0);
}

// ---------------- pass 0: fc f32 [d][j][i][g] -> fcb2 bf16 [sp][g][kg][j][8] ----------------
// Coalesced g-major reads (240B runs) + XOR-swizzled LDS transpose.
// Also zeroes the output buffer (replaces the separate hipMemsetAsync dispatch).
constexpr int TRG = 60;       // g per block; g0 = gc*60 -> 240B offset, 16B aligned
constexpr int TRTB = 512;
constexpr int TRUNITS = 256 * 15;   // row-pairs(256) x float4-chunks(15) == TRG*64 write units

__global__ __launch_bounds__(TRTB) void fkan_tr(const float* __restrict__ src,
                                                ushort* __restrict__ dst,
                                                float* __restrict__ outz) {
    __shared__ __align__(16) ushort L[TRG * 2 * 32 * 8];   // [gl][ih][djl][e] 60KB (swizzled)
    const int gc = blockIdx.x;            // 0..4
    const int sp = blockIdx.y;            // 0..7
    const int djc = blockIdx.z;           // 0..31
    const int dj0 = djc * 32;
    const int d = dj0 >> 9;
    const int j0 = dj0 & 511;
    const int g0 = gc * TRG;
    const int tid = threadIdx.x;

    // ---- fused output zeroing: 1280 blocks x 512 threads, one float4 each ----
    {
        size_t bid = (size_t)(djc * 8 + sp) * 5 + gc;          // 0..1279
        size_t zt = bid * TRTB + tid;                          // 0..655359
        if (zt < (size_t)B_N * J_N / 4)                        // 524288 float4s
            ((float4*)outz)[zt] = make_float4(0.f, 0.f, 0.f, 0.f);
    }

    unsigned int* Lw = (unsigned int*)L;

    // ---- read phase: lanes run along g -> contiguous 16B float4 loads ----
    auto rbody = [&](int u) {
        int rp = u / 15, c = u - rp * 15;           // rp = row-pair, c = float4 chunk
        int djl = rp >> 3, ilp = rp & 7;            // i = sp*16 + ilp*2 (+1)
        int ihl = ilp >> 2, e2 = ilp & 3;           // e = 2*e2 (lo), 2*e2+1 (hi)
        const float* p = src + ((size_t)(dj0 + djl) * 128 + sp * 16 + ilp * 2) * 300
                       + g0 + c * 4;
        float4 va = *(const float4*)p;              // row i,   4 g
        float4 vb = *(const float4*)(p + 300);      // row i+1, 4 g
        float a[4] = {va.x, va.y, va.z, va.w};
        float b[4] = {vb.x, vb.y, vb.z, vb.w};
        const int swz = (c & 7) << 2;               // XOR swizzle (word units), c = gl>>2
#pragma unroll
        for (int k = 0; k < 4; ++k) {
            int gl = c * 4 + k;
            int wd = ((gl * 2 + ihl) * 32 + djl) * 4 + e2;   // u32 word index
            Lw[wd ^ swz] = pack_bf2(a[k], b[k]);
        }
    };
#pragma unroll
    for (int it = 0; it < 7; ++it) rbody(tid + it * TRTB);   // uniform: 7*512 = 3584
    if (tid < TRUNITS - 7 * TRTB) rbody(tid + 7 * TRTB);     // tail 256
    __syncthreads();

    // ---- write phase: contiguous 512B runs per (g,kg); ds_read_b128 ----
    const uint4* Lv = (const uint4*)L;
    auto wbody = [&](int w) {
        int gl = w >> 6, r = w & 63;
        int ihl = r >> 5, jl = r & 31;
        int q = (gl * 64 + ihl * 32 + jl) ^ ((gl >> 2) & 7);  // same involution, uint4 units
        size_t d16 = ((size_t)(sp * G_N + g0 + gl) * 4 + d * 2 + ihl) * 512 + j0 + jl;
        ((uint4*)dst)[d16] = Lv[q];
    };
#pragma unroll
    for (int it = 0; it < 7; ++it) wbody(tid + it * TRTB);
    if (tid < TRG * 64 - 7 * TRTB) wbody(tid + 7 * TRTB);
}

// ---------------- fused trig GEMM: B direct global->VGPR, A-only LDS ----------------
// ROUND-9: waves retiled 1x8 over J (wave tile 128x64) so each j-column is owned by
// exactly ONE wave -> B loads go global->register (L2-hot, no duplication), the whole
// Bt LDS round-trip (DMA + ds_read, ~1150 cyc/CU/step of the ~2540 cadence) is gone.
// LDS holds only the double-buffered At (16KB). Barrier/dbuf skeleton unchanged (r1).
// B regs double-buffered (bA/bB, static indexing). writeA remapped (q4=tid&3,
// m=tid>>2): per-wave stores = two 256B-contiguous runs -> 2-way (free), fixes r8's
// 4.9M bank conflicts.
__global__ __launch_bounds__(TBG, 2)
void fkan_gemm(const float* __restrict__ x,
               const ushort* __restrict__ fcb,
               float* __restrict__ out) {
    __shared__ __align__(16) ushort At[2 * 4 * 128 * 8];  // 16KB dbuf [buf][kg][m][8]

    const int tid = threadIdx.x;
    const int bm = blockIdx.x, sp = blockIdx.z;
    const int lane = tid & 63, wid = tid >> 6;           // 8 waves, wave = 64-col j-stripe
    const int lhi = lane >> 4, llo = lane & 15;

    // ---- A-gen mapping: 4 elems per thread, conflict-free At writes ----
    const int m = tid >> 2;                  // 0..127
    const int q4 = tid & 3;                  // elem quartet
    const int ihq = q4 >> 1, eq = (q4 & 1) * 4;

    // ---- init rotation state: k=1, 4 elems per thread ----
    float sv[4], cv[4], s0[4], c0[4];
    {
        const float* xr = x + ((size_t)(bm * BM + m)) * I_N + sp * IC + q4 * 4;
        float4 xa = *(const float4*)xr;
        float xv[4] = {xa.x, xa.y, xa.z, xa.w};
#pragma unroll
        for (int j = 0; j < 4; ++j) {
            float r = fract_(xv[j] * INV2PI);
            s0[j] = __builtin_amdgcn_sinf(r);
            c0[j] = __builtin_amdgcn_cosf(r);
            sv[j] = s0[j];
            cv[j] = c0[j];
        }
    }

    ushort* awc0 = &At[(ihq * 128 + m) * 8 + eq];        // kg = ihq     (cos), 4 elems
    ushort* aws0 = &At[((2 + ihq) * 128 + m) * 8 + eq];  // kg = 2 + ihq (sin)

    // ---- B lane base: [g][kg=lhi][j = wid*64 + t*16 + llo][8] ----
    const ushort* bbase = fcb + (size_t)sp * SPSTRIDE
                        + ((size_t)lhi * 512 + wid * 64 + llo) * 8;
    auto loadB = [&](short8* br, int g) {
        const ushort* p = bbase + (size_t)g * GSTRIDE;
#pragma unroll
        for (int t = 0; t < 4; ++t)
            br[t] = *(const short8*)(p + t * 128);       // t*16 j * 8 ushorts
    };

    const int aoff = (lhi * 128 + llo) * 8;              // m = t*16 + llo via +t*128

    f32x4 acc[8][4];
#pragma unroll
    for (int a = 0; a < 8; ++a)
#pragma unroll
        for (int b = 0; b < 4; ++b) acc[a][b] = (f32x4){0.f, 0.f, 0.f, 0.f};

    // store current state (angle (k)x for upcoming step) then rotate by x
    auto writeA = [&](int nb) {
        uint2 vc = {pack_bf2(cv[0], cv[1]), pack_bf2(cv[2], cv[3])};
        *(uint2*)(awc0 + nb * 4096) = vc;
        uint2 vs = {pack_bf2(sv[0], sv[1]), pack_bf2(sv[2], sv[3])};
        *(uint2*)(aws0 + nb * 4096) = vs;
#pragma unroll
        for (int j = 0; j < 4; ++j) {
            float t = __builtin_fmaf(sv[j], c0[j], cv[j] * s0[j]);
            cv[j] = __builtin_fmaf(cv[j], c0[j], -(sv[j] * s0[j]));
            sv[j] = t;
        }
    };

    short8 bA[4], bB[4];

    // one g-step: consume At[cb] + bcur; prefetch B(gnext) into bnxt; gen A(gnext)
    auto halfstep = [&](int cb, short8* bcur, short8* bnxt, int gnext, bool doNext) {
        __syncthreads();   // publishes At buf cb
        if (doNext) loadB(bnxt, gnext);      // vmem prefetch; latency hides under MFMA
        short8 af[8];
#pragma unroll
        for (int t = 0; t < 8; ++t)
            af[t] = *(const short8*)&At[cb * 4096 + aoff + t * 128];
#pragma unroll
        for (int tm = 0; tm < 8; ++tm)
#pragma unroll
            for (int tn = 0; tn < 4; ++tn)
                acc[tm][tn] = __builtin_amdgcn_mfma_f32_16x16x32_bf16(
                    af[tm], bcur[tn], acc[tm][tn], 0, 0, 0);
        if (doNext) writeA(cb ^ 1);          // A-gen VALU overlaps MFMA burst
    };

    // prologue: A(0) (k=1) into buf0; B(0) into bA
    writeA(0);
    loadB(bA, 0);

    for (int g = 0; g < G_N; g += 2) {
        halfstep(0, bA, bB, g + 1, true);            // consume g   (g+1 <= 299 valid)
        halfstep(1, bB, bA, g + 2, g + 2 < G_N);     // consume g+1
    }

    const int row0 = bm * BM + lhi * 4;
    const int col0 = wid * 64 + llo;
#pragma unroll
    for (int tm = 0; tm < 8; ++tm)
#pragma unroll
        for (int tn = 0; tn < 4; ++tn)
#pragma unroll
            for (int r = 0; r < 4; ++r)
                atomicAdd(&out[(size_t)(row0 + tm * 16 + r) * J_N + col0 + tn * 16],
                          acc[tm][tn][r]);
}

// ---------------- fallback (ws too small): fp32-direct ----------------
constexpr int SPL_FB = 4;
constexpr int KS_FB = 2 * K1 / SPL_FB;
constexpr int NSTEP_FB = KS_FB / 32;

__global__ __launch_bounds__(TB)
void fkan_gemm_fb(const float* __restrict__ x,
                  const float* __restrict__ fc32,
                  float* __restrict__ out) {
    __shared__ float xs[128][65];
    __shared__ __align__(16) ushort At[4 * 128 * 8];
    __shared__ __align__(16) ushort Bt[4 * 128 * 8];

    const int tid = threadIdx.x;
    const int bm = blockIdx.x, bn = blockIdx.y, sp = blockIdx.z;
    const int d = sp >> 1;
    const int ib = (sp & 1) << 6;
    const int rbase = ib * G_N;

    for (int idx = tid; idx < 128 * 64; idx += TB) {
        int row = idx >> 6, il = idx & 63;
        xs[row][il] = x[(size_t)(bm * 128 + row) * I_N + ib + il];
    }

    f32x4 acc[4][4];
#pragma unroll
    for (int a = 0; a < 4; ++a)
#pragma unroll
        for (int b = 0; b < 4; ++b) acc[a][b] = (f32x4){0.f, 0.f, 0.f, 0.f};

    const int lane = tid & 63, wid = tid >> 6;
    const int wm = wid & 1, wn = wid >> 1;
    const int lhi = lane >> 4, llo = lane & 15;
    const int am = tid & 127, akg0 = tid >> 7;

    const float* f32base = fc32 + ((size_t)d * J_N + bn * 128) * K1 + rbase;

    for (int step = 0; step < NSTEP_FB; ++step) {
        __syncthreads();
#pragma unroll
        for (int it = 0; it < 2; ++it) {
            const int kg = akg0 + it * 2;
            int r = rbase + step * 32 + kg * 8;
            int i = (int)((unsigned)r / 300u);
            int g = r - i * 300;
            float xxv = xs[am][i - ib];
            float kkf = (float)(g + 1);
            short8 avv;
#pragma unroll
            for (int j = 0; j < 8; ++j) {
                float rev = xxv * kkf * INV2PI;
                float fr = fract_(rev) + (d ? 0.0f : 0.25f);
                avv[j] = (short)f2bf(__builtin_amdgcn_sinf(fract_(fr)));
                if (j < 7) {
                    ++g; kkf += 1.0f;
                    if (g == 300) { g = 0; kkf = 1.0f; ++i; xxv = xs[am][i - ib]; }
                }
            }
            *(short8*)&At[(kg * 128 + am) * 8] = avv;
        }
#pragma unroll
        for (int it = 0; it < 2; ++it) {
            int item = tid + it * TB;
            int n = item >> 2, grp = item & 3;
            const float* gp = f32base + (size_t)n * K1 + step * 32 + grp * 8;
            float4 v0 = *(const float4*)gp;
            float4 v1 = *(const float4*)(gp + 4);
            short8 bv;
            bv[0] = (short)f2bf(v0.x); bv[1] = (short)f2bf(v0.y);
            bv[2] = (short)f2bf(v0.z); bv[3] = (short)f2bf(v0.w);
            bv[4] = (short)f2bf(v1.x); bv[5] = (short)f2bf(v1.y);
            bv[6] = (short)f2bf(v1.z); bv[7] = (short)f2bf(v1.w);
            *(short8*)&Bt[(grp * 128 + n) * 8] = bv;
        }
        __syncthreads();
        short8 af[4], bf[4];
#pragma unroll
        for (int t = 0; t < 4; ++t) {
            af[t] = *(const short8*)&At[(lhi * 128 + wm * 64 + t * 16 + llo) * 8];
            bf[t] = *(const short8*)&Bt[(lhi * 128 + wn * 64 + t * 16 + llo) * 8];
        }
#pragma unroll
        for (int tm = 0; tm < 4; ++tm)
#pragma unroll
            for (int tn = 0; tn < 4; ++tn)
                acc[tm][tn] = __builtin_amdgcn_mfma_f32_16x16x32_bf16(
                    af[tm], bf[tn], acc[tm][tn], 0, 0, 0);
    }

    const int row0 = bm * 128 + wm * 64 + lhi * 4;
    const int col0 = bn * 128 + wn * 64 + llo;
#pragma unroll
    for (int tm = 0; tm < 4; ++tm)
#pragma unroll
        for (int tn = 0; tn < 4; ++tn)
#pragma unroll
            for (int r = 0; r < 4; ++r)
                atomicAdd(&out[(size_t)(row0 + tm * 16 + r) * J_N + col0 + tn * 16],
                          acc[tm][tn][r]);
}

extern "C" void kernel_launch(void* const* d_in, const int* in_sizes, int n_in,
                              void* d_out, int out_size, void* d_ws, size_t ws_size,
                              hipStream_t stream) {
    const float* x = (const float*)d_in[0];
    const float* fc = (const float*)d_in[1];
    float* out = (float*)d_out;

    const size_t need = (size_t)2 * J_N * K1 * sizeof(ushort);  // 78.6 MB

    if (ws_size >= need) {
        ushort* fcb = (ushort*)d_ws;
        // fkan_tr zeroes `out` as well (replaces hipMemsetAsync dispatch)
        fkan_tr<<<dim3(5, 8, 32), TRTB, 0, stream>>>(fc, fcb, out);   // 1280 blocks
        dim3 grid(B_N / BM, 1, NSP);                                  // 32 x 1 x 8 = 256
        fkan_gemm<<<grid, TBG, 0, stream>>>(x, fcb, out);
    } else {
        hipMemsetAsync(d_out, 0, (size_t)out_size * sizeof(float), stream);
        dim3 grid(B_N / 128, J_N / 128, SPL_FB);
        fkan_gemm_fb<<<grid, TB, 0, stream>>>(x, fc, out);
    }
}

// Round 10
// 512.686 us; speedup vs baseline: 1.0330x; 1.0330x over previous
//
#include <hip/hip_runtime.h>
#include <hip/hip_bf16.h>
#include <cstdint>

#define TB 256
#define TBG 512

typedef short short8 __attribute__((ext_vector_type(8)));
typedef float f32x4 __attribute__((ext_vector_type(4)));

constexpr int B_N = 4096, I_N = 128, J_N = 512, G_N = 300;
constexpr int K1 = I_N * G_N;            // 38400 per d
constexpr int BM = 128, BN = 512;        // full-J block; 8 waves 1x8 over J (wave tile 128x64)
constexpr int NSP = 8;                   // 8 i-chunks of 16
constexpr int IC = 16;
constexpr float INV2PI = 0.15915494309189535f;

// fcb2 layout: [sp][g][kg][j][8e] bf16, kg = d*2 + ih, i = sp*16 + ih*8 + e
constexpr int GSTRIDE = 4 * 512 * 8;                // ushorts per g = 16384
constexpr size_t SPSTRIDE = (size_t)G_N * GSTRIDE;  // per sp

__device__ __forceinline__ ushort f2bf(float f) {
    unsigned int u = __float_as_uint(f);
    return (ushort)((u + 0x7FFFu + ((u >> 16) & 1u)) >> 16);
}

__device__ __forceinline__ float fract_(float x) {
#if __has_builtin(__builtin_amdgcn_fractf)
    return __builtin_amdgcn_fractf(x);
#else
    return x - floorf(x);
#endif
}

// HW packed f32x2 -> bf16x2 (RNE) — v_cvt_pk_bf16_f32 on gfx950
__device__ __forceinline__ unsigned int pack_bf2(float a, float b) {
    __hip_bfloat162 h = __float22bfloat162_rn(make_float2(a, b));
    unsigned int u;
    __builtin_memcpy(&u, &h, 4);
    return u;
}

typedef __attribute__((address_space(3))) unsigned int lds_u32_t;
typedef __attribute__((address_space(1))) const unsigned int glb_u32_t;

__device__ __forceinline__ void llds16(const void* g, void* l) {
    __builtin_amdgcn_global_load_lds(
        reinterpret_cast<glb_u32_t*>(reinterpret_cast<uintptr_t>(g)),
        reinterpret_cast<lds_u32_t*>((unsigned int)reinterpret_cast<uintptr_t>(l)),
        16, 0, 0);
}

// ---------------- pass 0: fc f32 [d][j][i][g] -> fcb2 bf16 [sp][g][kg][j][8] ----------------
// Coalesced g-major reads (240B runs) + XOR-swizzled LDS transpose.
// Also zeroes the output buffer (replaces the separate hipMemsetAsync dispatch).
constexpr int TRG = 60;       // g per block; g0 = gc*60 -> 240B offset, 16B aligned
constexpr int TRTB = 512;
constexpr int TRUNITS = 256 * 15;   // row-pairs(256) x float4-chunks(15) == TRG*64 write units

__global__ __launch_bounds__(TRTB) void fkan_tr(const float* __restrict__ src,
                                                ushort* __restrict__ dst,
                                                float* __restrict__ outz) {
    __shared__ __align__(16) ushort L[TRG * 2 * 32 * 8];   // [gl][ih][djl][e] 60KB (swizzled)
    const int gc = blockIdx.x;            // 0..4
    const int sp = blockIdx.y;            // 0..7
    const int djc = blockIdx.z;           // 0..31
    const int dj0 = djc * 32;
    const int d = dj0 >> 9;
    const int j0 = dj0 & 511;
    const int g0 = gc * TRG;
    const int tid = threadIdx.x;

    // ---- fused output zeroing: 1280 blocks x 512 threads, one float4 each ----
    {
        size_t bid = (size_t)(djc * 8 + sp) * 5 + gc;          // 0..1279
        size_t zt = bid * TRTB + tid;                          // 0..655359
        if (zt < (size_t)B_N * J_N / 4)                        // 524288 float4s
            ((float4*)outz)[zt] = make_float4(0.f, 0.f, 0.f, 0.f);
    }

    unsigned int* Lw = (unsigned int*)L;

    // ---- read phase: lanes run along g -> contiguous 16B float4 loads ----
    auto rbody = [&](int u) {
        int rp = u / 15, c = u - rp * 15;           // rp = row-pair, c = float4 chunk
        int djl = rp >> 3, ilp = rp & 7;            // i = sp*16 + ilp*2 (+1)
        int ihl = ilp >> 2, e2 = ilp & 3;           // e = 2*e2 (lo), 2*e2+1 (hi)
        const float* p = src + ((size_t)(dj0 + djl) * 128 + sp * 16 + ilp * 2) * 300
                       + g0 + c * 4;
        float4 va = *(const float4*)p;              // row i,   4 g
        float4 vb = *(const float4*)(p + 300);      // row i+1, 4 g
        float a[4] = {va.x, va.y, va.z, va.w};
        float b[4] = {vb.x, vb.y, vb.z, vb.w};
        const int swz = (c & 7) << 2;               // XOR swizzle (word units), c = gl>>2
#pragma unroll
        for (int k = 0; k < 4; ++k) {
            int gl = c * 4 + k;
            int wd = ((gl * 2 + ihl) * 32 + djl) * 4 + e2;   // u32 word index
            Lw[wd ^ swz] = pack_bf2(a[k], b[k]);
        }
    };
#pragma unroll
    for (int it = 0; it < 7; ++it) rbody(tid + it * TRTB);   // uniform: 7*512 = 3584
    if (tid < TRUNITS - 7 * TRTB) rbody(tid + 7 * TRTB);     // tail 256
    __syncthreads();

    // ---- write phase: contiguous 512B runs per (g,kg); ds_read_b128 ----
    const uint4* Lv = (const uint4*)L;
    auto wbody = [&](int w) {
        int gl = w >> 6, r = w & 63;
        int ihl = r >> 5, jl = r & 31;
        int q = (gl * 64 + ihl * 32 + jl) ^ ((gl >> 2) & 7);  // same involution, uint4 units
        size_t d16 = ((size_t)(sp * G_N + g0 + gl) * 4 + d * 2 + ihl) * 512 + j0 + jl;
        ((uint4*)dst)[d16] = Lv[q];
    };
#pragma unroll
    for (int it = 0; it < 7; ++it) wbody(tid + it * TRTB);
    if (tid < TRG * 64 - 7 * TRTB) wbody(tid + 7 * TRTB);
}

// ---------------- fused trig GEMM: BK=64 (2 g per barrier), B in registers ----------------
// ROUND-10: r9 skeleton + interval = 2 g. Measured: per-g cadence 2688 cyc vs MFMA
// floor 1242 (MfmaUtil 46%) across three structures -> ~1400 cyc FIXED cost per
// barrier interval (barrier + af-latency ramp + aligned LDS burst). Halve the barrier
// count: At = [2buf][8 kgg][128][8] (32KB, kgg = (g&1)*4 + kg); writeA2 emits both
// next-interval A states; b0/b1 regs reloaded in place (WAR-safe: loads issue after
// their consuming MFMAs in program order; data lands a full interval before reuse).
__global__ __launch_bounds__(TBG, 2)
void fkan_gemm(const float* __restrict__ x,
               const ushort* __restrict__ fcb,
               float* __restrict__ out) {
    __shared__ __align__(16) ushort At[2 * 8 * 128 * 8];  // 32KB dbuf [buf][kgg][m][8]

    const int tid = threadIdx.x;
    const int bm = blockIdx.x, sp = blockIdx.z;
    const int lane = tid & 63, wid = tid >> 6;           // 8 waves, wave = 64-col j-stripe
    const int lhi = lane >> 4, llo = lane & 15;

    // ---- A-gen mapping: 4 elems per thread, conflict-light At writes ----
    const int m = tid >> 2;                  // 0..127
    const int q4 = tid & 3;                  // elem quartet
    const int ihq = q4 >> 1, eq = (q4 & 1) * 4;

    // ---- init rotation state: k=1, 4 elems per thread ----
    float sv[4], cv[4], s0[4], c0[4];
    {
        const float* xr = x + ((size_t)(bm * BM + m)) * I_N + sp * IC + q4 * 4;
        float4 xa = *(const float4*)xr;
        float xv[4] = {xa.x, xa.y, xa.z, xa.w};
#pragma unroll
        for (int j = 0; j < 4; ++j) {
            float r = fract_(xv[j] * INV2PI);
            s0[j] = __builtin_amdgcn_sinf(r);
            c0[j] = __builtin_amdgcn_cosf(r);
            sv[j] = s0[j];
            cv[j] = c0[j];
        }
    }

    ushort* awc0 = &At[(ihq * 128 + m) * 8 + eq];        // kg = ihq     (cos)
    ushort* aws0 = &At[((2 + ihq) * 128 + m) * 8 + eq];  // kg = 2 + ihq (sin)

    // ---- B lane base: [g][kg=lhi][j = wid*64 + t*16 + llo][8] ----
    const ushort* bbase = fcb + (size_t)sp * SPSTRIDE
                        + ((size_t)lhi * 512 + wid * 64 + llo) * 8;
    auto loadB = [&](short8* br, int g) {
        const ushort* p = bbase + (size_t)g * GSTRIDE;
#pragma unroll
        for (int t = 0; t < 4; ++t)
            br[t] = *(const short8*)(p + t * 128);       // t*16 j * 8 ushorts
    };

    const int aoff = (lhi * 128 + llo) * 8;              // m = t*16 + llo via +t*128

    f32x4 acc[8][4];
#pragma unroll
    for (int a = 0; a < 8; ++a)
#pragma unroll
        for (int b = 0; b < 4; ++b) acc[a][b] = (f32x4){0.f, 0.f, 0.f, 0.f};

    // store current state (angle kx) into buf nb, parity slot pr; then rotate by x
    auto putA = [&](int nb, int pr) {
        uint2 vc = {pack_bf2(cv[0], cv[1]), pack_bf2(cv[2], cv[3])};
        *(uint2*)(awc0 + nb * 8192 + pr * 4096) = vc;
        uint2 vs = {pack_bf2(sv[0], sv[1]), pack_bf2(sv[2], sv[3])};
        *(uint2*)(aws0 + nb * 8192 + pr * 4096) = vs;
#pragma unroll
        for (int j = 0; j < 4; ++j) {
            float t = __builtin_fmaf(sv[j], c0[j], cv[j] * s0[j]);
            cv[j] = __builtin_fmaf(cv[j], c0[j], -(sv[j] * s0[j]));
            sv[j] = t;
        }
    };

    short8 b0[4], b1[4];

    // prologue: A(k=1),A(k=2) into buf0; B(0),B(1) into regs
    putA(0, 0);
    putA(0, 1);
    loadB(b0, 0);
    loadB(b1, 1);

    for (int iv = 0; iv < G_N / 2; ++iv) {               // 150 intervals
        const int cb = iv & 1;
        const int gb = iv * 2;
        const bool more = iv < G_N / 2 - 1;
        __syncthreads();                                 // publishes At[cb]
        short8 af[8];
        // ---- g even (parity 0) ----
#pragma unroll
        for (int t = 0; t < 8; ++t)
            af[t] = *(const short8*)&At[cb * 8192 + aoff + t * 128];
#pragma unroll
        for (int tm = 0; tm < 8; ++tm)
#pragma unroll
            for (int tn = 0; tn < 4; ++tn)
                acc[tm][tn] = __builtin_amdgcn_mfma_f32_16x16x32_bf16(
                    af[tm], b0[tn], acc[tm][tn], 0, 0, 0);
        if (more) loadB(b0, gb + 2);                     // b0 free; prefetch next even
        // ---- g odd (parity 1) ----
#pragma unroll
        for (int t = 0; t < 8; ++t)
            af[t] = *(const short8*)&At[cb * 8192 + 4096 + aoff + t * 128];
#pragma unroll
        for (int tm = 0; tm < 8; ++tm)
#pragma unroll
            for (int tn = 0; tn < 4; ++tn)
                acc[tm][tn] = __builtin_amdgcn_mfma_f32_16x16x32_bf16(
                    af[tm], b1[tn], acc[tm][tn], 0, 0, 0);
        if (more) {
            loadB(b1, gb + 3);                           // prefetch next odd
            putA(cb ^ 1, 0);                             // A states for next interval
            putA(cb ^ 1, 1);                             // (VALU overlaps other waves' MFMA)
        }
    }

    const int row0 = bm * BM + lhi * 4;
    const int col0 = wid * 64 + llo;
#pragma unroll
    for (int tm = 0; tm < 8; ++tm)
#pragma unroll
        for (int tn = 0; tn < 4; ++tn)
#pragma unroll
            for (int r = 0; r < 4; ++r)
                atomicAdd(&out[(size_t)(row0 + tm * 16 + r) * J_N + col0 + tn * 16],
                          acc[tm][tn][r]);
}

// ---------------- fallback (ws too small): fp32-direct ----------------
constexpr int SPL_FB = 4;
constexpr int KS_FB = 2 * K1 / SPL_FB;
constexpr int NSTEP_FB = KS_FB / 32;

__global__ __launch_bounds__(TB)
void fkan_gemm_fb(const float* __restrict__ x,
                  const float* __restrict__ fc32,
                  float* __restrict__ out) {
    __shared__ float xs[128][65];
    __shared__ __align__(16) ushort At[4 * 128 * 8];
    __shared__ __align__(16) ushort Bt[4 * 128 * 8];

    const int tid = threadIdx.x;
    const int bm = blockIdx.x, bn = blockIdx.y, sp = blockIdx.z;
    const int d = sp >> 1;
    const int ib = (sp & 1) << 6;
    const int rbase = ib * G_N;

    for (int idx = tid; idx < 128 * 64; idx += TB) {
        int row = idx >> 6, il = idx & 63;
        xs[row][il] = x[(size_t)(bm * 128 + row) * I_N + ib + il];
    }

    f32x4 acc[4][4];
#pragma unroll
    for (int a = 0; a < 4; ++a)
#pragma unroll
        for (int b = 0; b < 4; ++b) acc[a][b] = (f32x4){0.f, 0.f, 0.f, 0.f};

    const int lane = tid & 63, wid = tid >> 6;
    const int wm = wid & 1, wn = wid >> 1;
    const int lhi = lane >> 4, llo = lane & 15;
    const int am = tid & 127, akg0 = tid >> 7;

    const float* f32base = fc32 + ((size_t)d * J_N + bn * 128) * K1 + rbase;

    for (int step = 0; step < NSTEP_FB; ++step) {
        __syncthreads();
#pragma unroll
        for (int it = 0; it < 2; ++it) {
            const int kg = akg0 + it * 2;
            int r = rbase + step * 32 + kg * 8;
            int i = (int)((unsigned)r / 300u);
            int g = r - i * 300;
            float xxv = xs[am][i - ib];
            float kkf = (float)(g + 1);
            short8 avv;
#pragma unroll
            for (int j = 0; j < 8; ++j) {
                float rev = xxv * kkf * INV2PI;
                float fr = fract_(rev) + (d ? 0.0f : 0.25f);
                avv[j] = (short)f2bf(__builtin_amdgcn_sinf(fract_(fr)));
                if (j < 7) {
                    ++g; kkf += 1.0f;
                    if (g == 300) { g = 0; kkf = 1.0f; ++i; xxv = xs[am][i - ib]; }
                }
            }
            *(short8*)&At[(kg * 128 + am) * 8] = avv;
        }
#pragma unroll
        for (int it = 0; it < 2; ++it) {
            int item = tid + it * TB;
            int n = item >> 2, grp = item & 3;
            const float* gp = f32base + (size_t)n * K1 + step * 32 + grp * 8;
            float4 v0 = *(const float4*)gp;
            float4 v1 = *(const float4*)(gp + 4);
            short8 bv;
            bv[0] = (short)f2bf(v0.x); bv[1] = (short)f2bf(v0.y);
            bv[2] = (short)f2bf(v0.z); bv[3] = (short)f2bf(v0.w);
            bv[4] = (short)f2bf(v1.x); bv[5] = (short)f2bf(v1.y);
            bv[6] = (short)f2bf(v1.z); bv[7] = (short)f2bf(v1.w);
            *(short8*)&Bt[(grp * 128 + n) * 8] = bv;
        }
        __syncthreads();
        short8 af[4], bf[4];
#pragma unroll
        for (int t = 0; t < 4; ++t) {
            af[t] = *(const short8*)&At[(lhi * 128 + wm * 64 + t * 16 + llo) * 8];
            bf[t] = *(const short8*)&Bt[(lhi * 128 + wn * 64 + t * 16 + llo) * 8];
        }
#pragma unroll
        for (int tm = 0; tm < 4; ++tm)
#pragma unroll
            for (int tn = 0; tn < 4; ++tn)
                acc[tm][tn] = __builtin_amdgcn_mfma_f32_16x16x32_bf16(
                    af[tm], bf[tn], acc[tm][tn], 0, 0, 0);
    }

    const int row0 = bm * 128 + wm * 64 + lhi * 4;
    const int col0 = bn * 128 + wn * 64 + llo;
#pragma unroll
    for (int tm = 0; tm < 4; ++tm)
#pragma unroll
        for (int tn = 0; tn < 4; ++tn)
#pragma unroll
            for (int r = 0; r < 4; ++r)
                atomicAdd(&out[(size_t)(row0 + tm * 16 + r) * J_N + col0 + tn * 16],
                          acc[tm][tn][r]);
}

extern "C" void kernel_launch(void* const* d_in, const int* in_sizes, int n_in,
                              void* d_out, int out_size, void* d_ws, size_t ws_size,
                              hipStream_t stream) {
    const float* x = (const float*)d_in[0];
    const float* fc = (const float*)d_in[1];
    float* out = (float*)d_out;

    const size_t need = (size_t)2 * J_N * K1 * sizeof(ushort);  // 78.6 MB

    if (ws_size >= need) {
        ushort* fcb = (ushort*)d_ws;
        // fkan_tr zeroes `out` as well (replaces hipMemsetAsync dispatch)
        fkan_tr<<<dim3(5, 8, 32), TRTB, 0, stream>>>(fc, fcb, out);   // 1280 blocks
        dim3 grid(B_N / BM, 1, NSP);                                  // 32 x 1 x 8 = 256
        fkan_gemm<<<grid, TBG, 0, stream>>>(x, fcb, out);
    } else {
        hipMemsetAsync(d_out, 0, (size_t)out_size * sizeof(float), stream);
        dim3 grid(B_N / 128, J_N / 128, SPL_FB);
        fkan_gemm_fb<<<grid, TB, 0, stream>>>(x, fc, out);
    }
}